// Round 6
// baseline (430.333 us; speedup 1.0000x reference)
//
#include <hip/hip_runtime.h>
#include <hip/hip_bf16.h>

#define NB 60000
#define NP 2000
#define NC 4000
#define EM_N 150000
#define EP_N 300000
#define EI_N 150000
#define POOL_N (EM_N + EP_N + EI_N)
#define SEG_TOT (NB + NB + NC)                        // 124000 segment counters
#define SCAN_BLK 1024
#define NPART ((SEG_TOT + SCAN_BLK - 1) / SCAN_BLK)   // 122

typedef __hip_bfloat16 bf16;
typedef __attribute__((ext_vector_type(8))) short s8v;   // 8 bf16 raw bits (4 VGPRs)
typedef __attribute__((ext_vector_type(4))) float f4v;

__device__ __forceinline__ float toF(float x) { return x; }
__device__ __forceinline__ float toF(bf16 x) { return __bfloat162float(x); }
__device__ __forceinline__ void stC(float* C, size_t idx, float v) { C[idx] = v; }
__device__ __forceinline__ void stC(bf16* C, size_t idx, float v) { C[idx] = __float2bfloat16(v); }
__device__ __forceinline__ short f2bs(float f) {
    bf16 h = __float2bfloat16(f);
    return __builtin_bit_cast(short, h);
}
__device__ __forceinline__ float bsToF(short s) {
    return __builtin_bit_cast(float, ((unsigned)(unsigned short)s) << 16);
}

// ---------------- generic VALU GEMM (small M): C[M,128] = A[M,128] @ W[128,128] ----------------
template<typename AT, typename CT, bool BIAS>
__global__ void gemm128_kernel(const AT* __restrict__ A, const float* __restrict__ W,
                               const float* __restrict__ bias, CT* __restrict__ C, int M) {
    __shared__ float Al[16 * 128];
    const int tid = threadIdx.x;
    const int row0 = blockIdx.x * 16;
    for (int i = tid; i < 16 * 128; i += 256) {
        int r = row0 + (i >> 7);
        Al[i] = (r < M) ? toF(A[(size_t)r * 128 + (i & 127)]) : 0.f;
    }
    __syncthreads();
    const int col = tid & 127, rg = tid >> 7;
    float acc[8];
#pragma unroll
    for (int i = 0; i < 8; i++) acc[i] = 0.f;
    for (int k = 0; k < 128; k++) {
        float w = W[k * 128 + col];
#pragma unroll
        for (int i = 0; i < 8; i++) acc[i] += Al[(rg * 8 + i) * 128 + k] * w;
    }
    float bv = 0.f;
    if constexpr (BIAS) bv = bias[col];
#pragma unroll
    for (int i = 0; i < 8; i++) {
        int r = row0 + rg * 8 + i;
        if (r < M) stC(C, (size_t)r * 128 + col, acc[i] + bv);
    }
}

// ---------------- weight prep: Wt[w][n][k] = W_w[k][n] as bf16 bits ----------------
__global__ void wt_prep_kernel(const float* __restrict__ W0, const float* __restrict__ W1,
                               const float* __restrict__ W2, const float* __restrict__ W3,
                               const float* __restrict__ W4, ushort* __restrict__ Wt) {
    int t = blockIdx.x * 256 + threadIdx.x;
    if (t >= 5 * 16384) return;
    int w = t >> 14, r = t & 16383, k = r >> 7, n = r & 127;
    const float* W = (w == 0) ? W0 : (w == 1) ? W1 : (w == 2) ? W2 : (w == 3) ? W3 : W4;
    Wt[w * 16384 + n * 128 + k] = (ushort)f2bs(W[k * 128 + n]);
}

// ---------------- MFMA fused 5-matrix GEMM on x_ball ----------------
// Outputs: xr[NB,128], q[NB,128], kv[NB,256] (k|v interleaved), skip[NB,128], all bf16.
__global__ __launch_bounds__(256) void gemm5_mfma_kernel(
    const float* __restrict__ A, const ushort* __restrict__ Wt,
    const float* __restrict__ bq, const float* __restrict__ bk,
    const float* __restrict__ bv_, const float* __restrict__ bskip,
    bf16* __restrict__ xrB, bf16* __restrict__ qB, bf16* __restrict__ kvB,
    bf16* __restrict__ skipB) {
    const int lane = threadIdx.x & 63;
    const int wv = threadIdx.x >> 6;
    const int quad = lane >> 4, l16 = lane & 15;
    const int mbase = blockIdx.x * 128 + wv * 32;

    s8v a[2][4];
#pragma unroll
    for (int mt = 0; mt < 2; mt++) {
        int row = mbase + mt * 16 + l16;
        if (row >= NB) row = NB - 1;
        const float* ap = A + (size_t)row * 128 + quad * 8;
#pragma unroll
        for (int kt = 0; kt < 4; kt++) {
            const float4* p = (const float4*)(ap + kt * 32);
            float4 u = p[0], v = p[1];
            s8v f;
            f[0] = f2bs(u.x); f[1] = f2bs(u.y); f[2] = f2bs(u.z); f[3] = f2bs(u.w);
            f[4] = f2bs(v.x); f[5] = f2bs(v.y); f[6] = f2bs(v.z); f[7] = f2bs(v.w);
            a[mt][kt] = f;
        }
    }

#pragma unroll
    for (int w = 0; w < 5; w++) {
        const ushort* wt = Wt + w * 16384;
        bf16* op; const float* bp; int stride;
        if (w == 0)      { op = xrB;       bp = nullptr; stride = 128; }
        else if (w == 1) { op = qB;        bp = bq;      stride = 128; }
        else if (w == 2) { op = kvB;       bp = bk;      stride = 256; }
        else if (w == 3) { op = kvB + 128; bp = bv_;     stride = 256; }
        else             { op = skipB;     bp = bskip;   stride = 128; }
#pragma unroll
        for (int nt = 0; nt < 8; nt++) {
            int col = nt * 16 + l16;
            s8v b[4];
#pragma unroll
            for (int kt = 0; kt < 4; kt++)
                b[kt] = *(const s8v*)(wt + col * 128 + kt * 32 + quad * 8);
            float bval = bp ? bp[col] : 0.f;
#pragma unroll
            for (int mt = 0; mt < 2; mt++) {
                f4v acc = {0.f, 0.f, 0.f, 0.f};
#pragma unroll
                for (int kt = 0; kt < 4; kt++)
                    acc = __builtin_amdgcn_mfma_f32_16x16x32_bf16(a[mt][kt], b[kt], acc, 0, 0, 0);
#pragma unroll
                for (int r = 0; r < 4; r++) {
                    int row = mbase + mt * 16 + quad * 4 + r;
                    if (row < NB)
                        op[(size_t)row * stride + col] = __float2bfloat16(acc[r] + bval);
                }
            }
        }
    }
}

// ---------------- CSR build ----------------
__global__ void hist_all_kernel(const int* __restrict__ em, const int* __restrict__ ep,
                                const int* __restrict__ ei, int* __restrict__ counts) {
    int t = blockIdx.x * 256 + threadIdx.x;
    if (t < EM_N) atomicAdd(&counts[em[EM_N + t]], 1);
    else if (t < EM_N + EP_N) atomicAdd(&counts[NB + ep[EP_N + (t - EM_N)]], 1);
    else if (t < POOL_N) atomicAdd(&counts[2 * NB + ei[EI_N + (t - EM_N - EP_N)]], 1);
}

__global__ void scan1_kernel(const int* __restrict__ counts, int* __restrict__ offsets,
                             int* __restrict__ partials) {
    __shared__ int sd[256];
    int b = blockIdx.x, tid = threadIdx.x;
    int base = b * SCAN_BLK + tid * 4;
    int v[4]; int ts = 0;
#pragma unroll
    for (int j = 0; j < 4; j++) { int idx = base + j; v[j] = (idx < SEG_TOT) ? counts[idx] : 0; ts += v[j]; }
    sd[tid] = ts;
    for (int off = 1; off < 256; off <<= 1) {
        __syncthreads(); int t = (tid >= off) ? sd[tid - off] : 0;
        __syncthreads(); sd[tid] += t;
    }
    int run = sd[tid] - ts;
#pragma unroll
    for (int j = 0; j < 4; j++) { int idx = base + j; if (idx < SEG_TOT) offsets[idx] = run; run += v[j]; }
    if (tid == 255) partials[b] = sd[255];
}

__global__ void scan2_kernel(int* __restrict__ partials) {
    __shared__ int sd[256];
    int tid = threadIdx.x;
    int v = (tid < NPART) ? partials[tid] : 0;
    sd[tid] = v;
    for (int off = 1; off < 256; off <<= 1) {
        __syncthreads(); int t = (tid >= off) ? sd[tid - off] : 0;
        __syncthreads(); sd[tid] += t;
    }
    if (tid < NPART) partials[tid] = sd[tid] - v;
}

__global__ void scan3_kernel(int* __restrict__ offsets, const int* __restrict__ partials,
                             int* __restrict__ cursors) {
    int t = blockIdx.x * 256 + threadIdx.x;
    if (t >= SEG_TOT) return;
    int o = offsets[t] + partials[t >> 10];
    offsets[t] = o;
    cursors[t] = o;
}

// fill: store resolved src + dst (+ edge attr) in destination-sorted pool order
__global__ void fill_all_kernel(const int* __restrict__ em, const int* __restrict__ ep,
                                const int* __restrict__ ei, const float* __restrict__ ea_p,
                                int* __restrict__ cursors, int* __restrict__ psrc,
                                int* __restrict__ pdst, float* __restrict__ pea) {
    int t = blockIdx.x * 256 + threadIdx.x;
    int seg, s, d; float ea = 0.f;
    if (t < EM_N) { s = em[t]; d = em[EM_N + t]; seg = d; }
    else if (t < EM_N + EP_N) { int e = t - EM_N; s = ep[e]; d = ep[EP_N + e]; seg = NB + d; ea = ea_p[e]; }
    else if (t < POOL_N) { int e = t - EM_N - EP_N; s = ei[e]; d = ei[EI_N + e]; seg = 2 * NB + d; }
    else return;
    int pos = atomicAdd(&cursors[seg], 1);
    psrc[pos] = s; pdst[pos] = d; pea[pos] = ea;
}

// ---------------- edge-parallel GAT logits -> exp, pool-ordered ----------------
__global__ void gat_elog_kernel(const bf16* __restrict__ xl, const bf16* __restrict__ xr,
                                const float* __restrict__ att,
                                const int* __restrict__ psrc, const int* __restrict__ pdst,
                                float* __restrict__ elogM) {
    int t = blockIdx.x * 256 + threadIdx.x;
    if (t >= EM_N * 4) return;
    int pos = t >> 2, h = t & 3;
    int s = psrc[pos], d = pdst[pos];
    const ushort* lp = (const ushort*)xl + (size_t)s * 128 + h * 32;
    const ushort* rp = (const ushort*)xr + (size_t)d * 128 + h * 32;
    const float* ap = att + h * 32;
    float acc = 0.f;
#pragma unroll
    for (int kt = 0; kt < 4; kt++) {
        s8v lv = *(const s8v*)(lp + kt * 8);
        s8v rv = *(const s8v*)(rp + kt * 8);
#pragma unroll
        for (int j = 0; j < 8; j++) {
            float u = bsToF(lv[j]) + bsToF(rv[j]);
            u = u > 0.f ? u : 0.2f * u;
            acc += u * ap[kt * 8 + j];
        }
    }
    elogM[t] = __expf(acc);
}

// ---------------- edge-parallel TR logits -> exp, pool-ordered ----------------
__global__ void tr_elog_kernel(const bf16* __restrict__ q, const bf16* __restrict__ kv,
                               const float* __restrict__ We,
                               const int* __restrict__ psrc, const int* __restrict__ pdst,
                               const float* __restrict__ pea, float* __restrict__ elogP) {
    int t = blockIdx.x * 256 + threadIdx.x;
    if (t >= EP_N * 4) return;
    int pp = t >> 2, h = t & 3;
    int pos = EM_N + pp;
    int s = psrc[pos], d = pdst[pos];
    float ea = pea[pos];
    const ushort* kp = (const ushort*)kv + (size_t)s * 256 + h * 32;
    const ushort* qp = (const ushort*)q + (size_t)d * 128 + h * 32;
    const float* wp = We + h * 32;
    float acc = 0.f;
#pragma unroll
    for (int kt = 0; kt < 4; kt++) {
        s8v kf = *(const s8v*)(kp + kt * 8);
        s8v qf = *(const s8v*)(qp + kt * 8);
#pragma unroll
        for (int j = 0; j < 8; j++)
            acc += bsToF(qf[j]) * (bsToF(kf[j]) + ea * wp[kt * 8 + j]);
    }
    elogP[t] = __expf(acc * 0.17677669529663687f);  // 1/sqrt(32)
}

// ---------------- ball aggregation: GAT-agg + TR-agg + skip + residual + LN ----------------
__global__ void ball_agg_kernel(
    const bf16* __restrict__ xl, const bf16* __restrict__ kv, const bf16* __restrict__ skip,
    const float* __restrict__ x_ball, const float* __restrict__ g_b, const float* __restrict__ We,
    const int* __restrict__ offsets, const int* __restrict__ counts,
    const int* __restrict__ psrc, const float* __restrict__ pea,
    const float* __restrict__ elogM, const float* __restrict__ elogP,
    const float* __restrict__ ln_g, const float* __restrict__ ln_b, float* __restrict__ out) {
    int gid = blockIdx.x * 256 + threadIdx.x;
    int d = gid >> 6, l = gid & 63;
    if (d >= NB) return;
    bool hi = (l >= 32);
    size_t rowD = (size_t)d * 128;

    // ---- GATv2 aggregation ----
    int beg = offsets[d], cnt = counts[d];
    float n0 = 0.f, n1 = 0.f, de0 = 0.f, de1 = 0.f;
    for (int j = 0; j < cnt; j++) {
        int pos = beg + j;
        int s = psrc[pos];
        float4 pe = *(const float4*)(elogM + (size_t)pos * 4);
        float p0 = hi ? pe.y : pe.x, p1 = hi ? pe.w : pe.z;
        const ushort* xp = (const ushort*)xl + (size_t)s * 128;
        n0 += p0 * bsToF(xp[l]); n1 += p1 * bsToF(xp[l + 64]);
        de0 += p0; de1 += p1;
    }
    float gat0 = n0 / (de0 + 1e-16f), gat1 = n1 / (de1 + 1e-16f);

    // ---- TransformerConv aggregation (v-half of kv) ----
    beg = offsets[NB + d]; cnt = counts[NB + d];
    float sv0 = 0.f, sv1 = 0.f, sp0 = 0.f, sp1 = 0.f;
    de0 = de1 = 0.f;
    for (int j = 0; j < cnt; j++) {
        int pos = beg + j;
        int s = psrc[pos];
        float ea = pea[pos];
        float4 pe = *(const float4*)(elogP + (size_t)(pos - EM_N) * 4);
        float p0 = hi ? pe.y : pe.x, p1 = hi ? pe.w : pe.z;
        const ushort* vp = (const ushort*)kv + (size_t)s * 256 + 128;
        sv0 += p0 * bsToF(vp[l]); sv1 += p1 * bsToF(vp[l + 64]);
        sp0 += p0 * ea; sp1 += p1 * ea;
        de0 += p0; de1 += p1;
    }
    float w0 = We[l], w1 = We[l + 64];
    float tr0 = (sv0 + sp0 * w0) / (de0 + 1e-16f);
    float tr1 = (sv1 + sp1 * w1) / (de1 + 1e-16f);

    // ---- sum + LayerNorm ----
    float val0 = toF(skip[rowD + l]) + gat0 + tr0 + x_ball[rowD + l] + g_b[l];
    float val1 = toF(skip[rowD + l + 64]) + gat1 + tr1 + x_ball[rowD + l + 64] + g_b[l + 64];
    float s = val0 + val1;
#pragma unroll
    for (int m = 1; m <= 32; m <<= 1) s += __shfl_xor(s, m);
    float mu = s * (1.f / 128.f);
    float d0 = val0 - mu, d1 = val1 - mu;
    float qv = d0 * d0 + d1 * d1;
#pragma unroll
    for (int m = 1; m <= 32; m <<= 1) qv += __shfl_xor(qv, m);
    float inv = rsqrtf(qv * (1.f / 128.f) + 1e-5f);
    out[rowD + l] = d0 * inv * ln_g[l] + ln_b[l];
    out[rowD + l + 64] = d1 * inv * ln_g[l + 64] + ln_b[l + 64];
}

// ---------------- SAGE gather, 4-way edge split per node ----------------
__global__ void sage_gather4_kernel(const float* __restrict__ x_ball,
                                    const int* __restrict__ offsets, const int* __restrict__ counts,
                                    const int* __restrict__ psrc, float* __restrict__ summ) {
    __shared__ float part[4][128];
    int c = blockIdx.x;
    int w = threadIdx.x >> 6, l = threadIdx.x & 63;
    int beg = offsets[2 * NB + c], cnt = counts[2 * NB + c];
    float s0 = 0.f, s1 = 0.f;
    for (int j = w; j < cnt; j += 4) {
        int s = psrc[beg + j];
        size_t rs = (size_t)s * 128;
        s0 += x_ball[rs + l];
        s1 += x_ball[rs + l + 64];
    }
    part[w][l] = s0; part[w][l + 64] = s1;
    __syncthreads();
    if (w == 0) {
        float m = fmaxf((float)cnt, 1.f);
        size_t rowC = (size_t)c * 128;
        summ[rowC + l] = (part[0][l] + part[1][l] + part[2][l] + part[3][l]) / m;
        summ[rowC + l + 64] = (part[0][l + 64] + part[1][l + 64] + part[2][l + 64] + part[3][l + 64]) / m;
    }
}

// ---------------- fused ctx: xc@Wr + summ@Wl + bl + residual + LN ----------------
__global__ void ctx_fused_kernel(const float* __restrict__ xc, const float* __restrict__ summ,
                                 const float* __restrict__ Wr, const float* __restrict__ Wl,
                                 const float* __restrict__ bl,
                                 const float* __restrict__ g, const float* __restrict__ b,
                                 float* __restrict__ out) {
    __shared__ float A0[16 * 128];
    __shared__ float A1[16 * 128];
    __shared__ float CB[16 * 128];
    const int tid = threadIdx.x;
    const int row0 = blockIdx.x * 16;
    for (int i = tid; i < 16 * 128; i += 256) {
        int r = row0 + (i >> 7);
        A0[i] = (r < NC) ? xc[(size_t)r * 128 + (i & 127)] : 0.f;
        A1[i] = (r < NC) ? summ[(size_t)r * 128 + (i & 127)] : 0.f;
    }
    __syncthreads();
    const int col = tid & 127, rg = tid >> 7;
    float acc[8];
#pragma unroll
    for (int i = 0; i < 8; i++) acc[i] = 0.f;
    for (int k = 0; k < 128; k++) {
        float w0 = Wr[k * 128 + col], w1 = Wl[k * 128 + col];
#pragma unroll
        for (int i = 0; i < 8; i++)
            acc[i] += A0[(rg * 8 + i) * 128 + k] * w0 + A1[(rg * 8 + i) * 128 + k] * w1;
    }
    float bv = bl[col];
#pragma unroll
    for (int i = 0; i < 8; i++)
        CB[(rg * 8 + i) * 128 + col] = acc[i] + bv + A0[(rg * 8 + i) * 128 + col];  // + residual
    __syncthreads();
    // LayerNorm: wave wv handles rows wv*4..wv*4+3
    const int wv = tid >> 6, l = tid & 63;
    for (int r = 0; r < 4; r++) {
        int lr = wv * 4 + r, row = row0 + lr;
        if (row >= NC) break;
        float v0 = CB[lr * 128 + l], v1 = CB[lr * 128 + l + 64];
        float s = v0 + v1;
#pragma unroll
        for (int m = 1; m <= 32; m <<= 1) s += __shfl_xor(s, m);
        float mu = s * (1.f / 128.f);
        float d0 = v0 - mu, d1 = v1 - mu;
        float qv = d0 * d0 + d1 * d1;
#pragma unroll
        for (int m = 1; m <= 32; m <<= 1) qv += __shfl_xor(qv, m);
        float inv = rsqrtf(qv * (1.f / 128.f) + 1e-5f);
        out[(size_t)row * 128 + l] = d0 * inv * g[l] + b[l];
        out[(size_t)row * 128 + l + 64] = d1 * inv * g[l + 64] + b[l + 64];
    }
}

__global__ void copy_player_kernel(const float* __restrict__ xp, float* __restrict__ out) {
    int t = blockIdx.x * 256 + threadIdx.x;
    if (t >= NP * 128) return;
    out[t] = xp[t];
}

extern "C" void kernel_launch(void* const* d_in, const int* in_sizes, int n_in,
                              void* d_out, int out_size, void* d_ws, size_t ws_size,
                              hipStream_t stream) {
    const float* x_ball = (const float*)d_in[0];
    const float* x_player = (const float*)d_in[1];
    const float* x_context = (const float*)d_in[2];
    const int* em = (const int*)d_in[3];
    const int* ep = (const int*)d_in[4];
    const int* ei = (const int*)d_in[5];
    const float* ea_p = (const float*)d_in[6];
    const float* g_Wl = (const float*)d_in[7];
    const float* g_Wr = (const float*)d_in[8];
    const float* g_att = (const float*)d_in[9];
    const float* g_b = (const float*)d_in[10];
    const float* t_Wq = (const float*)d_in[11];
    const float* t_bq = (const float*)d_in[12];
    const float* t_Wk = (const float*)d_in[13];
    const float* t_bk = (const float*)d_in[14];
    const float* t_Wv = (const float*)d_in[15];
    const float* t_bv = (const float*)d_in[16];
    const float* t_We = (const float*)d_in[17];
    const float* t_Wskip = (const float*)d_in[18];
    const float* t_bskip = (const float*)d_in[19];
    const float* s_Wl = (const float*)d_in[20];
    const float* s_bl = (const float*)d_in[21];
    const float* s_Wr = (const float*)d_in[22];
    const float* ln_ball_g = (const float*)d_in[23];
    const float* ln_ball_b = (const float*)d_in[24];
    const float* ln_ctx_g = (const float*)d_in[25];
    const float* ln_ctx_b = (const float*)d_in[26];
    float* out = (float*)d_out;

    // ---- workspace (~95 MB) ----
    float* ws = (float*)d_ws;
    size_t o = 0;
    float* summ = ws + o;     o += (size_t)NC * 128;
    float* pea = ws + o;      o += POOL_N;
    float* elogM = ws + o;    o += (size_t)EM_N * 4;
    float* elogP = ws + o;    o += (size_t)EP_N * 4;
    int* counts = (int*)(ws + o);   o += SEG_TOT;
    int* offsets = (int*)(ws + o);  o += SEG_TOT;
    int* cursors = (int*)(ws + o);  o += SEG_TOT;
    int* partials = (int*)(ws + o); o += 128;
    int* psrc = (int*)(ws + o);     o += POOL_N;
    int* pdst = (int*)(ws + o);     o += POOL_N;
    ushort* Wt = (ushort*)(ws + o); o += (5 * 16384) / 2;
    bf16* bws = (bf16*)(ws + o);
    size_t ob = 0;
    bf16* xl = bws + ob;    ob += (size_t)NP * 128;
    bf16* xrB = bws + ob;   ob += (size_t)NB * 128;
    bf16* qB = bws + ob;    ob += (size_t)NB * 128;
    bf16* kvB = bws + ob;   ob += (size_t)NB * 256;   // k|v interleaved per node
    bf16* skipB = bws + ob; ob += (size_t)NB * 128;

    dim3 blk(256);
    // ---- CSR build ----
    hipMemsetAsync(counts, 0, SEG_TOT * sizeof(int), stream);
    hist_all_kernel<<<(POOL_N + 255) / 256, blk, 0, stream>>>(em, ep, ei, counts);
    scan1_kernel<<<NPART, blk, 0, stream>>>(counts, offsets, partials);
    scan2_kernel<<<1, blk, 0, stream>>>(partials);
    scan3_kernel<<<(SEG_TOT + 255) / 256, blk, 0, stream>>>(offsets, partials, cursors);
    fill_all_kernel<<<(POOL_N + 255) / 256, blk, 0, stream>>>(em, ep, ei, ea_p, cursors, psrc, pdst, pea);

    // ---- dense projections ----
    wt_prep_kernel<<<(5 * 16384 + 255) / 256, blk, 0, stream>>>(g_Wr, t_Wq, t_Wk, t_Wv, t_Wskip, Wt);
    gemm128_kernel<float, bf16, false><<<(NP + 15) / 16, blk, 0, stream>>>(x_player, g_Wl, nullptr, xl, NP);
    gemm5_mfma_kernel<<<(NB + 127) / 128, blk, 0, stream>>>(x_ball, Wt, t_bq, t_bk, t_bv, t_bskip,
                                                            xrB, qB, kvB, skipB);

    // ---- edge-parallel logits ----
    gat_elog_kernel<<<(EM_N * 4 + 255) / 256, blk, 0, stream>>>(xl, xrB, g_att, psrc, pdst, elogM);
    tr_elog_kernel<<<(EP_N * 4 + 255) / 256, blk, 0, stream>>>(qB, kvB, t_We, psrc, pdst, pea, elogP);

    // ---- ball aggregation + LN ----
    ball_agg_kernel<<<(NB * 64 + 255) / 256, blk, 0, stream>>>(
        xl, kvB, skipB, x_ball, g_b, t_We, offsets, counts, psrc, pea,
        elogM, elogP, ln_ball_g, ln_ball_b, out);

    // ---- SAGE -> ctx (fused GEMM+residual+LN) ----
    sage_gather4_kernel<<<NC, blk, 0, stream>>>(x_ball, offsets, counts, psrc, summ);
    ctx_fused_kernel<<<(NC + 15) / 16, blk, 0, stream>>>(x_context, summ, s_Wr, s_Wl, s_bl,
                                                         ln_ctx_g, ln_ctx_b, out + (size_t)NB * 128);
    copy_player_kernel<<<(NP * 128 + 255) / 256, blk, 0, stream>>>(x_player,
                                                                   out + (size_t)(NB + NC) * 128);
}